// Round 1
// baseline (403.432 us; speedup 1.0000x reference)
//
#include <hip/hip_runtime.h>
#include <math.h>

#define NB      8192
#define ND      2048
#define NC      100
#define CP      128
#define RB      32
#define KC      32
#define ALPHA_  2.0f
#define MARGIN_ 0.05f

// ---------------- prep1: G = W^T W (100x100), pa = A @ W (100x100) ----------
__global__ __launch_bounds__(128) void k_prep1(const float* __restrict__ W,
                                               const float* __restrict__ A,
                                               float* __restrict__ G,
                                               float* __restrict__ pa) {
  __shared__ float wcol[128];
  __shared__ float arow[128];
  const int r = blockIdx.x;   // 0..99
  const int t = threadIdx.x;  // 0..127
  float g = 0.f, p = 0.f;
  for (int k0 = 0; k0 < ND; k0 += 128) {
    __syncthreads();
    wcol[t] = W[(k0 + t) * NC + r];
    arow[t] = A[r * ND + k0 + t];
    __syncthreads();
    if (t < NC) {
#pragma unroll 8
      for (int kk = 0; kk < 128; ++kk) {
        const float w = W[(k0 + kk) * NC + t];
        g = fmaf(wcol[kk], w, g);
        p = fmaf(arow[kk], w, p);
      }
    }
  }
  if (t < NC) {
    G[r * NC + t]  = g;
    pa[r * NC + t] = p;
  }
}

// ---------------- prep2: T=softmax(pa)-I ; Ut[c'][r] = (G T^T)[r][c'] -------
__global__ __launch_bounds__(128) void k_prep2(const float* __restrict__ G,
                                               const float* __restrict__ pa,
                                               float* __restrict__ Ut) {
  __shared__ float vals[CP];
  __shared__ float tl[CP];
  const int cp = blockIdx.x;  // row of pa == column of U
  const int t  = threadIdx.x;
  const float v = (t < NC) ? pa[cp * NC + t] : -INFINITY;
  vals[t] = v;
  __syncthreads();
  float m = -INFINITY;
  for (int c = 0; c < NC; ++c) m = fmaxf(m, vals[c]);
  float se = 0.f;
  for (int c = 0; c < NC; ++c) se += expf(vals[c] - m);
  tl[t] = (t < NC) ? (expf(v - m) / se - (t == cp ? 1.f : 0.f)) : 0.f;
  __syncthreads();
  if (t < NC) {
    float u = 0.f;
    // G is symmetric: U[r][cp] = sum_c G[r][c]*T[cp][c] = sum_c G[c][r]*tl[c]
    for (int c = 0; c < NC; ++c) u = fmaf(G[c * NC + t], tl[c], u);
    Ut[cp * NC + t] = u;  // Ut[cp][r] = U[r][cp]
  }
}

// ---------------- main: px = x@W, softmax, ce, ap, S_total, cls_ap ----------
__global__ __launch_bounds__(256) void k_main(const float* __restrict__ X,
                                              const float* __restrict__ W,
                                              const int* __restrict__ Y,
                                              const float* __restrict__ Ut,
                                              float* __restrict__ S_total,
                                              float* __restrict__ cls_ap,
                                              float* __restrict__ sums) {
  __shared__ float xl[RB][KC];
  __shared__ float wl[KC][CP];
  __shared__ int   yl[RB];
  __shared__ float stacc[CP];
  __shared__ float blkce, blkap;

  const int t    = threadIdx.x;
  const int cg   = t & 31;   // class group 0..31
  const int rg   = t >> 5;   // row group 0..7 (4 rows each)
  const int row0 = blockIdx.x * RB;

  if (t < RB) yl[t] = Y[row0 + t];
  if (t < CP) stacc[t] = 0.f;
  if (t == 0) { blkce = 0.f; blkap = 0.f; }

  float acc[4][4];  // [class j][row j2]
#pragma unroll
  for (int a = 0; a < 4; ++a)
#pragma unroll
    for (int b = 0; b < 4; ++b) acc[a][b] = 0.f;

  const int sr = t >> 3;        // x-stage row 0..31
  const int sk = (t & 7) * 4;   // x-stage col

  for (int k0 = 0; k0 < ND; k0 += KC) {
    __syncthreads();
    const float4 xv =
        *reinterpret_cast<const float4*>(&X[(size_t)(row0 + sr) * ND + k0 + sk]);
    *reinterpret_cast<float4*>(&xl[sr][sk]) = xv;
    for (int idx = t; idx < KC * CP; idx += 256) {
      const int kk = idx >> 7;
      const int c  = idx & 127;
      wl[kk][c] = (c < NC) ? W[(k0 + kk) * NC + c] : 0.f;
    }
    __syncthreads();
#pragma unroll 8
    for (int kk = 0; kk < KC; ++kk) {
      float wv[4], xr[4];
#pragma unroll
      for (int jc = 0; jc < 4; ++jc) wv[jc] = wl[kk][cg + 32 * jc];
#pragma unroll
      for (int j2 = 0; j2 < 4; ++j2) xr[j2] = xl[rg * 4 + j2][kk];
#pragma unroll
      for (int jc = 0; jc < 4; ++jc)
#pragma unroll
        for (int j2 = 0; j2 < 4; ++j2)
          acc[jc][j2] = fmaf(wv[jc], xr[j2], acc[jc][j2]);
    }
  }
  __syncthreads();

  // ---- per-row softmax + stats (row r lives in a 32-lane half-wave) ----
  const int c0 = cg, c1 = cg + 32, c2 = cg + 64, c3 = cg + 96;
  const bool v3 = (c3 < NC);
  float st0 = 0.f, st1 = 0.f, st2 = 0.f, st3 = 0.f;

#pragma unroll
  for (int j2 = 0; j2 < 4; ++j2) {
    const int r  = rg * 4 + j2;
    const int yr = yl[r];
    const float p0 = acc[0][j2], p1 = acc[1][j2], p2 = acc[2][j2];
    const float p3 = v3 ? acc[3][j2] : -INFINITY;
    float m = fmaxf(fmaxf(p0, p1), fmaxf(p2, p3));
#pragma unroll
    for (int off = 16; off > 0; off >>= 1) m = fmaxf(m, __shfl_xor(m, off));

    const float e0 = expf(p0 - m), e1 = expf(p1 - m), e2 = expf(p2 - m);
    const float e3 = v3 ? expf(acc[3][j2] - m) : 0.f;
    float se = e0 + e1 + e2 + e3;
    float py = (c0 == yr ? p0 : 0.f) + (c1 == yr ? p1 : 0.f) +
               (c2 == yr ? p2 : 0.f) + ((v3 && c3 == yr) ? acc[3][j2] : 0.f);
#pragma unroll
    for (int off = 16; off > 0; off >>= 1) {
      se += __shfl_xor(se, off);
      py += __shfl_xor(py, off);
    }
    const float ce  = m + logf(se) - py;
    const float inv = 1.f / se;
    const float s0 = e0 * inv - (c0 == yr ? 1.f : 0.f);
    const float s1 = e1 * inv - (c1 == yr ? 1.f : 0.f);
    const float s2 = e2 * inv - (c2 == yr ? 1.f : 0.f);
    const float s3 = v3 ? (e3 * inv - (c3 == yr ? 1.f : 0.f)) : 0.f;

    const float* uty = &Ut[yr * NC];  // Ut[yr][c] = U[c][yr]
    float ap = s0 * uty[c0] + s1 * uty[c1] + s2 * uty[c2] +
               (v3 ? s3 * uty[c3] : 0.f);
#pragma unroll
    for (int off = 16; off > 0; off >>= 1) ap += __shfl_xor(ap, off);

    if (cg == 0) {
      atomicAdd(&blkce, ce);
      atomicAdd(&blkap, ap);
      atomicAdd(&cls_ap[yr], ap);
    }
    st0 += s0; st1 += s1; st2 += s2; st3 += s3;
  }

  atomicAdd(&stacc[c0], st0);
  atomicAdd(&stacc[c1], st1);
  atomicAdd(&stacc[c2], st2);
  if (v3) atomicAdd(&stacc[c3], st3);
  __syncthreads();
  if (t < NC) atomicAdd(&S_total[t], stacc[t]);
  if (t == 0) {
    atomicAdd(&sums[0], blkce);
    atomicAdd(&sums[1], blkap);
  }
}

// ---------------- final: counts, V[c], loss --------------------------------
__global__ __launch_bounds__(256) void k_final(const int* __restrict__ Y,
                                               const float* __restrict__ Ut,
                                               const float* __restrict__ S_total,
                                               const float* __restrict__ cls_ap,
                                               const float* __restrict__ sums,
                                               float* __restrict__ out) {
  __shared__ int   hist[NC];
  __shared__ float st[NC];
  __shared__ float red[256];
  const int t = threadIdx.x;
  if (t < NC) { hist[t] = 0; st[t] = S_total[t]; }
  __syncthreads();
  for (int i = t; i < NB; i += 256) atomicAdd(&hist[Y[i]], 1);
  __syncthreads();
  float part = 0.f;
  if (t < NC) {
    float dot = 0.f;
    for (int r = 0; r < NC; ++r) dot = fmaf(st[r], Ut[t * NC + r], dot);
    part = (float)hist[t] * (dot - cls_ap[t]);
  }
  red[t] = part;
  __syncthreads();
  for (int off = 128; off > 0; off >>= 1) {
    if (t < off) red[t] += red[t + off];
    __syncthreads();
  }
  if (t == 0) {
    out[0] = (sums[0] + ALPHA_ * (red[0] - sums[1] + (float)NB * MARGIN_)) /
             (float)NB;
  }
}

extern "C" void kernel_launch(void* const* d_in, const int* in_sizes, int n_in,
                              void* d_out, int out_size, void* d_ws,
                              size_t ws_size, hipStream_t stream) {
  const float* X = (const float*)d_in[0];
  const float* W = (const float*)d_in[1];
  const float* A = (const float*)d_in[2];
  const int*   Y = (const int*)d_in[3];
  float* out = (float*)d_out;
  char*  ws  = (char*)d_ws;

  float* G       = (float*)(ws + 0);          // 100*100*4 = 40000
  float* pa      = (float*)(ws + 40960);      // 40000
  float* Ut      = (float*)(ws + 81920);      // 40000
  float* S_total = (float*)(ws + 122880);     // 400
  float* cls_ap  = (float*)(ws + 122880 + 512);
  float* sums    = (float*)(ws + 122880 + 1024);  // [ce, ap]

  hipMemsetAsync(ws + 122880, 0, 1536, stream);
  k_prep1<<<NC, 128, 0, stream>>>(W, A, G, pa);
  k_prep2<<<NC, 128, 0, stream>>>(G, pa, Ut);
  k_main<<<NB / RB, 256, 0, stream>>>(X, W, Y, Ut, S_total, cls_ap, sums);
  k_final<<<1, 256, 0, stream>>>(Y, Ut, S_total, cls_ap, sums, out);
}

// Round 2
// 135.435 us; speedup vs baseline: 2.9788x; 2.9788x over previous
//
#include <hip/hip_runtime.h>
#include <math.h>

#define NB      8192
#define ND      2048
#define NC      100
#define NCP     112
#define CP      128
#define ALPHA_  2.0f
#define MARGIN_ 0.05f

typedef short bf16x8 __attribute__((ext_vector_type(8)));
typedef float f32x4 __attribute__((ext_vector_type(4)));

static __device__ __forceinline__ unsigned short f2bf(float f) {
  unsigned u = __float_as_uint(f);
  u += 0x7FFFu + ((u >> 16) & 1u);
  return (unsigned short)(u >> 16);
}

// ---------------- prepw: Wt[c][k] = bf16(W[k][c]), c padded to 112 ----------
__global__ __launch_bounds__(256) void k_prepw(const float* __restrict__ W,
                                               unsigned short* __restrict__ Wt) {
  const int idx = blockIdx.x * 256 + threadIdx.x;  // 112*2048 total
  const int c = idx % NCP;
  const int k = idx / NCP;
  const float v = (c < NC) ? W[k * NC + c] : 0.f;
  Wt[(size_t)c * ND + k] = f2bf(v);
}

// ---------------- prep1: G = W^T W (100x100), pa = A @ W (100x100) ----------
__global__ __launch_bounds__(128) void k_prep1(const float* __restrict__ W,
                                               const float* __restrict__ A,
                                               float* __restrict__ G,
                                               float* __restrict__ pa) {
  __shared__ float wcol[128];
  __shared__ float arow[128];
  const int r = blockIdx.x;
  const int t = threadIdx.x;
  float g = 0.f, p = 0.f;
  for (int k0 = 0; k0 < ND; k0 += 128) {
    __syncthreads();
    wcol[t] = W[(k0 + t) * NC + r];
    arow[t] = A[r * ND + k0 + t];
    __syncthreads();
    if (t < NC) {
#pragma unroll 8
      for (int kk = 0; kk < 128; ++kk) {
        const float w = W[(k0 + kk) * NC + t];
        g = fmaf(wcol[kk], w, g);
        p = fmaf(arow[kk], w, p);
      }
    }
  }
  if (t < NC) {
    G[r * NC + t]  = g;
    pa[r * NC + t] = p;
  }
}

// ---------------- prep2: T=softmax(pa)-I ; Ut[cp][r] = (G T^T)[r][cp] -------
__global__ __launch_bounds__(128) void k_prep2(const float* __restrict__ G,
                                               const float* __restrict__ pa,
                                               float* __restrict__ Ut) {
  __shared__ float vals[CP];
  __shared__ float tl[CP];
  const int cp = blockIdx.x;
  const int t  = threadIdx.x;
  const float v = (t < NC) ? pa[cp * NC + t] : -INFINITY;
  vals[t] = v;
  __syncthreads();
  float m = -INFINITY;
  for (int c = 0; c < NC; ++c) m = fmaxf(m, vals[c]);
  float se = 0.f;
  for (int c = 0; c < NC; ++c) se += expf(vals[c] - m);
  tl[t] = (t < NC) ? (expf(v - m) / se - (t == cp ? 1.f : 0.f)) : 0.f;
  __syncthreads();
  if (t < NC) {
    float u = 0.f;
    for (int c = 0; c < NC; ++c) u = fmaf(G[c * NC + t], tl[c], u);
    Ut[cp * NC + t] = u;
  }
}

// ---------------- main: MFMA px = X@W + fused softmax/ce/ap/stats -----------
__global__ __launch_bounds__(128, 1) void k_main(const float* __restrict__ X,
                                                 const unsigned short* __restrict__ Wt,
                                                 const int* __restrict__ Y,
                                                 const float* __restrict__ Ut,
                                                 float* __restrict__ S_total,
                                                 float* __restrict__ cls_ap,
                                                 float* __restrict__ sums) {
  __shared__ float stacc[NCP];
  __shared__ float blkce, blkap;
  const int t    = threadIdx.x;
  const int w    = t >> 6;      // wave 0/1
  const int lane = t & 63;
  const int r    = lane & 15;   // A-row / B-col / D-col within tile
  const int g    = lane >> 4;   // k-quarter 0..3

  if (t < NCP) stacc[t] = 0.f;
  if (t == 0) { blkce = 0.f; blkap = 0.f; }

  const int grow0 = blockIdx.x * 32 + w * 16;
  const float* __restrict__ xrow = X + (size_t)(grow0 + r) * ND;
  const int koff = g * 8;

  f32x4 acc[7];
  const f32x4 z = {0.f, 0.f, 0.f, 0.f};
#pragma unroll
  for (int i = 0; i < 7; ++i) acc[i] = z;

  // register double-buffer: loads for k+32 in flight during MFMA of k
  float4 a0 = *(const float4*)(xrow + koff);
  float4 a1 = *(const float4*)(xrow + koff + 4);
  bf16x8 bfr[7];
#pragma unroll
  for (int i = 0; i < 7; ++i)
    bfr[i] = *(const bf16x8*)(Wt + (size_t)(i * 16 + r) * ND + koff);

  for (int k0 = 0; k0 < ND; k0 += 32) {
    const float4 ca0 = a0, ca1 = a1;
    bf16x8 cb[7];
#pragma unroll
    for (int i = 0; i < 7; ++i) cb[i] = bfr[i];
    const int kn = k0 + 32;
    if (kn < ND) {
      a0 = *(const float4*)(xrow + kn + koff);
      a1 = *(const float4*)(xrow + kn + koff + 4);
#pragma unroll
      for (int i = 0; i < 7; ++i)
        bfr[i] = *(const bf16x8*)(Wt + (size_t)(i * 16 + r) * ND + kn + koff);
    }
    bf16x8 af;
    af[0] = (short)f2bf(ca0.x); af[1] = (short)f2bf(ca0.y);
    af[2] = (short)f2bf(ca0.z); af[3] = (short)f2bf(ca0.w);
    af[4] = (short)f2bf(ca1.x); af[5] = (short)f2bf(ca1.y);
    af[6] = (short)f2bf(ca1.z); af[7] = (short)f2bf(ca1.w);
#pragma unroll
    for (int i = 0; i < 7; ++i)
      acc[i] = __builtin_amdgcn_mfma_f32_16x16x32_bf16(af, cb[i], acc[i], 0, 0, 0);
  }

  // ---- fused epilogue: per row (row = g*4 + j), 16-lane-group reduces ----
  const bool v6 = (96 + r) < NC;
  float st[7];
#pragma unroll
  for (int i = 0; i < 7; ++i) st[i] = 0.f;

#pragma unroll
  for (int j = 0; j < 4; ++j) {
    const int grow = grow0 + g * 4 + j;
    const int yr   = Y[grow];
    float v[7];
#pragma unroll
    for (int i = 0; i < 7; ++i) v[i] = acc[i][j];

    float m = -INFINITY;
#pragma unroll
    for (int i = 0; i < 6; ++i) m = fmaxf(m, v[i]);
    if (v6) m = fmaxf(m, v[6]);
#pragma unroll
    for (int off = 8; off > 0; off >>= 1) m = fmaxf(m, __shfl_xor(m, off));

    float e[7];
    float se = 0.f, py = 0.f;
#pragma unroll
    for (int i = 0; i < 7; ++i) {
      const bool valid = (i < 6) | v6;
      e[i] = valid ? __expf(v[i] - m) : 0.f;
      se += e[i];
      if (i * 16 + r == yr) py = v[i];
    }
#pragma unroll
    for (int off = 8; off > 0; off >>= 1) {
      se += __shfl_xor(se, off);
      py += __shfl_xor(py, off);
    }
    const float ce  = m + __logf(se) - py;
    const float inv = 1.f / se;

    const float* __restrict__ uty = Ut + yr * NC;
    float ap = 0.f;
    float s[7];
#pragma unroll
    for (int i = 0; i < 7; ++i) {
      const int col = i * 16 + r;
      s[i] = e[i] * inv - (col == yr ? 1.f : 0.f);
      const float u = ((i < 6) | v6) ? uty[col] : 0.f;
      ap = fmaf(s[i], u, ap);
      st[i] += s[i];
    }
#pragma unroll
    for (int off = 8; off > 0; off >>= 1) ap += __shfl_xor(ap, off);

    if (r == 0) {
      atomicAdd(&blkce, ce);
      atomicAdd(&blkap, ap);
      atomicAdd(&cls_ap[yr], ap);
    }
  }

#pragma unroll
  for (int i = 0; i < 7; ++i) atomicAdd(&stacc[i * 16 + r], st[i]);
  __syncthreads();
  if (t < NC) atomicAdd(&S_total[t], stacc[t]);
  if (t == 0) {
    atomicAdd(&sums[0], blkce);
    atomicAdd(&sums[1], blkap);
  }
}

// ---------------- final: counts, V[c], loss --------------------------------
__global__ __launch_bounds__(256) void k_final(const int* __restrict__ Y,
                                               const float* __restrict__ Ut,
                                               const float* __restrict__ S_total,
                                               const float* __restrict__ cls_ap,
                                               const float* __restrict__ sums,
                                               float* __restrict__ out) {
  __shared__ int   hist[NC];
  __shared__ float st[NC];
  __shared__ float red[256];
  const int t = threadIdx.x;
  if (t < NC) { hist[t] = 0; st[t] = S_total[t]; }
  __syncthreads();
  for (int i = t; i < NB; i += 256) atomicAdd(&hist[Y[i]], 1);
  __syncthreads();
  float part = 0.f;
  if (t < NC) {
    float dot = 0.f;
    for (int r = 0; r < NC; ++r) dot = fmaf(st[r], Ut[t * NC + r], dot);
    part = (float)hist[t] * (dot - cls_ap[t]);
  }
  red[t] = part;
  __syncthreads();
  for (int off = 128; off > 0; off >>= 1) {
    if (t < off) red[t] += red[t + off];
    __syncthreads();
  }
  if (t == 0) {
    out[0] = (sums[0] + ALPHA_ * (red[0] - sums[1] + (float)NB * MARGIN_)) /
             (float)NB;
  }
}

extern "C" void kernel_launch(void* const* d_in, const int* in_sizes, int n_in,
                              void* d_out, int out_size, void* d_ws,
                              size_t ws_size, hipStream_t stream) {
  const float* X = (const float*)d_in[0];
  const float* W = (const float*)d_in[1];
  const float* A = (const float*)d_in[2];
  const int*   Y = (const int*)d_in[3];
  float* out = (float*)d_out;
  char*  ws  = (char*)d_ws;

  float*          G       = (float*)(ws + 0);
  float*          pa      = (float*)(ws + 40960);
  float*          Ut      = (float*)(ws + 81920);
  float*          S_total = (float*)(ws + 122880);
  float*          cls_ap  = (float*)(ws + 123392);
  float*          sums    = (float*)(ws + 123904);
  unsigned short* Wt      = (unsigned short*)(ws + 131072);  // 112*2048*2 B

  hipMemsetAsync(ws + 122880, 0, 1536, stream);
  k_prepw<<<(NCP * ND) / 256, 256, 0, stream>>>(W, Wt);
  k_prep1<<<NC, 128, 0, stream>>>(W, A, G, pa);
  k_prep2<<<NC, 128, 0, stream>>>(G, pa, Ut);
  k_main<<<NB / 32, 128, 0, stream>>>(X, Wt, Y, Ut, S_total, cls_ap, sums);
  k_final<<<1, 256, 0, stream>>>(Y, Ut, S_total, cls_ap, sums, out);
}

// Round 3
// 90.214 us; speedup vs baseline: 4.4719x; 1.5013x over previous
//
#include <hip/hip_runtime.h>
#include <math.h>

#define NB      8192
#define ND      2048
#define NC      100
#define NCP     112
#define ALPHA_  2.0f
#define MARGIN_ 0.05f

typedef short bf16x8 __attribute__((ext_vector_type(8)));
typedef float f32x4 __attribute__((ext_vector_type(4)));

static __device__ __forceinline__ unsigned short f2bf(float f) {
  unsigned u = __float_as_uint(f);
  u += 0x7FFFu + ((u >> 16) & 1u);
  return (unsigned short)(u >> 16);
}

// ---- fused prep: [0,112) W->Wt bf16 transpose; [112,512) G,pa k-split; ----
// ---- [512,544) label histogram                                          ----
__global__ __launch_bounds__(256) void k_prep(const float* __restrict__ W,
                                              const float* __restrict__ A,
                                              const int* __restrict__ Y,
                                              unsigned short* __restrict__ Wt,
                                              float* __restrict__ G,
                                              float* __restrict__ pa,
                                              int* __restrict__ ihist) {
  __shared__ float wcol[256];
  __shared__ float arow[256];
  const int bid = blockIdx.x;
  const int t   = threadIdx.x;
  if (bid < NCP) {
    const int c  = bid;
    const int k8 = t * 8;
    bf16x8 v;
#pragma unroll
    for (int u = 0; u < 8; ++u)
      v[u] = (short)((c < NC) ? f2bf(W[(size_t)(k8 + u) * NC + c]) : 0);
    *(bf16x8*)(Wt + (size_t)c * ND + k8) = v;
  } else if (bid < 512) {
    const int idx = bid - NCP;   // 0..399
    const int r   = idx >> 2;    // 0..99
    const int ks  = idx & 3;     // k-slice of 512
    float g = 0.f, p = 0.f;
    for (int k0 = ks * 512; k0 < ks * 512 + 512; k0 += 256) {
      __syncthreads();
      wcol[t] = W[(size_t)(k0 + t) * NC + r];
      arow[t] = A[(size_t)r * ND + k0 + t];
      __syncthreads();
      if (t < NC) {
#pragma unroll 8
        for (int kk = 0; kk < 256; ++kk) {
          const float w = W[(size_t)(k0 + kk) * NC + t];
          g = fmaf(wcol[kk], w, g);
          p = fmaf(arow[kk], w, p);
        }
      }
    }
    if (t < NC) {
      atomicAdd(&G[r * NC + t], g);
      atomicAdd(&pa[r * NC + t], p);
    }
  } else {
    const int i = (bid - 512) * 256 + t;
    atomicAdd(&ihist[Y[i]], 1);
  }
}

// ---------------- prep2: T=softmax(pa)-I ; Ut[cp][r] = (G T^T)[r][cp] -------
__global__ __launch_bounds__(128) void k_prep2(const float* __restrict__ G,
                                               const float* __restrict__ pa,
                                               float* __restrict__ Ut) {
  __shared__ float vals[128];
  __shared__ float tl[128];
  const int cp = blockIdx.x;
  const int t  = threadIdx.x;
  const float v = (t < NC) ? pa[cp * NC + t] : -INFINITY;
  vals[t] = v;
  __syncthreads();
  float m = -INFINITY;
  for (int c = 0; c < NC; ++c) m = fmaxf(m, vals[c]);
  float se = 0.f;
  for (int c = 0; c < NC; ++c) se += __expf(vals[c] - m);
  tl[t] = (t < NC) ? (__expf(v - m) / se - (t == cp ? 1.f : 0.f)) : 0.f;
  __syncthreads();
  if (t < NC) {
    float u = 0.f;
    for (int c = 0; c < NC; ++c) u = fmaf(G[c * NC + t], tl[c], u);
    Ut[cp * NC + t] = u;
  }
}

// ---- main: 16 rows/block, 8 waves k-split 256 each, LDS reduce, epilogue ---
__global__ __launch_bounds__(512, 4) void k_main(const float* __restrict__ X,
                                                 const unsigned short* __restrict__ Wt,
                                                 const int* __restrict__ Y,
                                                 const float* __restrict__ Ut,
                                                 float* __restrict__ S_total,
                                                 float* __restrict__ cls_ap,
                                                 float* __restrict__ sums) {
  __shared__ float red[8][7][4][64];
  __shared__ float stacc[NCP];
  __shared__ float blkce, blkap;

  const int t    = threadIdx.x;
  const int w    = t >> 6;     // wave 0..7 = K-slice
  const int lane = t & 63;
  const int r    = lane & 15;  // col-within-tile / A-row
  const int g    = lane >> 4;  // k-quarter / row-group

  if (t < NCP) stacc[t] = 0.f;
  if (t == 0) { blkce = 0.f; blkap = 0.f; }

  const int grow0 = blockIdx.x * 16;
  const float* __restrict__ xrow = X + (size_t)(grow0 + r) * ND + w * 256;
  const int koff = g * 8;

  f32x4 acc[7];
  const f32x4 z = {0.f, 0.f, 0.f, 0.f};
#pragma unroll
  for (int i = 0; i < 7; ++i) acc[i] = z;

  float4 a0 = *(const float4*)(xrow + koff);
  float4 a1 = *(const float4*)(xrow + koff + 4);
  bf16x8 bfr[7];
#pragma unroll
  for (int i = 0; i < 7; ++i)
    bfr[i] = *(const bf16x8*)(Wt + (size_t)(i * 16 + r) * ND + w * 256 + koff);

  for (int k0 = 0; k0 < 256; k0 += 32) {
    const float4 ca0 = a0, ca1 = a1;
    bf16x8 cb[7];
#pragma unroll
    for (int i = 0; i < 7; ++i) cb[i] = bfr[i];
    const int kn = k0 + 32;
    if (kn < 256) {
      a0 = *(const float4*)(xrow + kn + koff);
      a1 = *(const float4*)(xrow + kn + koff + 4);
#pragma unroll
      for (int i = 0; i < 7; ++i)
        bfr[i] = *(const bf16x8*)(Wt + (size_t)(i * 16 + r) * ND + w * 256 +
                                  kn + koff);
    }
    bf16x8 af;
    af[0] = (short)f2bf(ca0.x); af[1] = (short)f2bf(ca0.y);
    af[2] = (short)f2bf(ca0.z); af[3] = (short)f2bf(ca0.w);
    af[4] = (short)f2bf(ca1.x); af[5] = (short)f2bf(ca1.y);
    af[6] = (short)f2bf(ca1.z); af[7] = (short)f2bf(ca1.w);
#pragma unroll
    for (int i = 0; i < 7; ++i)
      acc[i] = __builtin_amdgcn_mfma_f32_16x16x32_bf16(af, cb[i], acc[i], 0, 0, 0);
  }

  // partials -> LDS (lane-contiguous innermost: conflict-free)
#pragma unroll
  for (int i = 0; i < 7; ++i)
#pragma unroll
    for (int j = 0; j < 4; ++j) red[w][i][j][lane] = acc[i][j];
  __syncthreads();

  // epilogue: waves 0..3 each own j = w (rows g*4 + j)
  if (w < 4) {
    const int j = w;
    float v[7];
#pragma unroll
    for (int i = 0; i < 7; ++i) {
      float s = 0.f;
#pragma unroll
      for (int w2 = 0; w2 < 8; ++w2) s += red[w2][i][j][lane];
      v[i] = s;
    }
    const bool v6   = (96 + r) < NC;
    const int  grow = grow0 + g * 4 + j;
    const int  yr   = Y[grow];

    float m = -INFINITY;
#pragma unroll
    for (int i = 0; i < 6; ++i) m = fmaxf(m, v[i]);
    if (v6) m = fmaxf(m, v[6]);
#pragma unroll
    for (int off = 8; off > 0; off >>= 1) m = fmaxf(m, __shfl_xor(m, off));

    float e[7];
    float se = 0.f, py = 0.f;
#pragma unroll
    for (int i = 0; i < 7; ++i) {
      const bool valid = (i < 6) | v6;
      e[i] = valid ? __expf(v[i] - m) : 0.f;
      se += e[i];
      if (i * 16 + r == yr) py = v[i];
    }
#pragma unroll
    for (int off = 8; off > 0; off >>= 1) {
      se += __shfl_xor(se, off);
      py += __shfl_xor(py, off);
    }
    const float ce  = m + __logf(se) - py;
    const float inv = 1.f / se;

    const float* __restrict__ uty = Ut + yr * NC;
    float ap = 0.f;
    float s[7];
#pragma unroll
    for (int i = 0; i < 7; ++i) {
      const int col = i * 16 + r;
      s[i] = e[i] * inv - (col == yr ? 1.f : 0.f);
      const float u = ((i < 6) | v6) ? uty[col] : 0.f;
      ap = fmaf(s[i], u, ap);
    }
#pragma unroll
    for (int off = 8; off > 0; off >>= 1) ap += __shfl_xor(ap, off);

    if (r == 0) {
      atomicAdd(&blkce, ce);
      atomicAdd(&blkap, ap);
      atomicAdd(&cls_ap[yr], ap);
    }
#pragma unroll
    for (int i = 0; i < 7; ++i) atomicAdd(&stacc[i * 16 + r], s[i]);
  }
  __syncthreads();
  if (t < NC) atomicAdd(&S_total[t], stacc[t]);
  if (t == 0) {
    atomicAdd(&sums[0], blkce);
    atomicAdd(&sums[1], blkap);
  }
}

// ---------------- final: V[c] dot + loss -----------------------------------
__global__ __launch_bounds__(128) void k_final(const int* __restrict__ ihist,
                                               const float* __restrict__ Ut,
                                               const float* __restrict__ S_total,
                                               const float* __restrict__ cls_ap,
                                               const float* __restrict__ sums,
                                               float* __restrict__ out) {
  __shared__ float st[NC];
  __shared__ float red[128];
  const int t = threadIdx.x;
  if (t < NC) st[t] = S_total[t];
  __syncthreads();
  float part = 0.f;
  if (t < NC) {
    float dot = 0.f;
    for (int r = 0; r < NC; ++r) dot = fmaf(st[r], Ut[t * NC + r], dot);
    part = (float)ihist[t] * (dot - cls_ap[t]);
  }
  red[t] = part;
  __syncthreads();
  for (int off = 64; off > 0; off >>= 1) {
    if (t < off) red[t] += red[t + off];
    __syncthreads();
  }
  if (t == 0) {
    out[0] = (sums[0] + ALPHA_ * (red[0] - sums[1] + (float)NB * MARGIN_)) /
             (float)NB;
  }
}

extern "C" void kernel_launch(void* const* d_in, const int* in_sizes, int n_in,
                              void* d_out, int out_size, void* d_ws,
                              size_t ws_size, hipStream_t stream) {
  const float* X = (const float*)d_in[0];
  const float* W = (const float*)d_in[1];
  const float* A = (const float*)d_in[2];
  const int*   Y = (const int*)d_in[3];
  float* out = (float*)d_out;
  char*  ws  = (char*)d_ws;

  float*          G       = (float*)(ws + 0);       // 40000 B
  float*          pa      = (float*)(ws + 40960);   // 40000 B
  float*          Ut      = (float*)(ws + 81920);   // 40000 B
  float*          S_total = (float*)(ws + 122880);  // 448 B
  float*          cls_ap  = (float*)(ws + 123392);  // 400 B
  float*          sums    = (float*)(ws + 123904);  // 8 B
  int*            ihist   = (int*)(ws + 124416);    // 400 B
  unsigned short* Wt      = (unsigned short*)(ws + 131072);  // 112*2048*2 B

  hipMemsetAsync(ws, 0, 124928, stream);
  k_prep<<<544, 256, 0, stream>>>(W, A, Y, Wt, G, pa, ihist);
  k_prep2<<<NC, 128, 0, stream>>>(G, pa, Ut);
  k_main<<<NB / 16, 512, 0, stream>>>(X, Wt, Y, Ut, S_total, cls_ap, sums);
  k_final<<<1, 128, 0, stream>>>(ihist, Ut, S_total, cls_ap, sums, out);
}

// Round 4
// 77.997 us; speedup vs baseline: 5.1724x; 1.1566x over previous
//
#include <hip/hip_runtime.h>
#include <math.h>

#define NB      8192
#define ND      2048
#define NC      100
#define NCP     112
#define ALPHA_  2.0f
#define MARGIN_ 0.05f

typedef short bf16x8 __attribute__((ext_vector_type(8)));
typedef float f32x4 __attribute__((ext_vector_type(4)));

static __device__ __forceinline__ unsigned short f2bf(float f) {
  unsigned u = __float_as_uint(f);
  u += 0x7FFFu + ((u >> 16) & 1u);
  return (unsigned short)(u >> 16);
}

// ---- fused prep ------------------------------------------------------------
// bid [0,112):   Wtf fragment-major bf16: frag f=(ws*7+i)*64+l holds
//                W[ws*32+(l>>4)*8+j][i*16+(l&15)], j=0..7 (zero-pad col>=100)
// bid [112,912): G = W^T W, pa = A @ W, K-split 8, atomics
// bid [912,944): label histogram
__global__ __launch_bounds__(256) void k_prep(const float* __restrict__ W,
                                              const float* __restrict__ A,
                                              const int* __restrict__ Y,
                                              unsigned short* __restrict__ Wtf,
                                              float* __restrict__ G,
                                              float* __restrict__ pa,
                                              int* __restrict__ ihist) {
  __shared__ float wcol[256];
  __shared__ float arow[256];
  const int bid = blockIdx.x;
  const int t   = threadIdx.x;
  if (bid < 112) {
    const int f   = bid * 256 + t;   // 0..28671
    const int ws  = f / 448;
    const int rem = f - ws * 448;
    const int i   = rem >> 6;
    const int l   = rem & 63;
    const int col = i * 16 + (l & 15);
    const int k0  = ws * 32 + (l >> 4) * 8;
    bf16x8 v;
#pragma unroll
    for (int j = 0; j < 8; ++j)
      v[j] = (short)((col < NC) ? f2bf(W[(size_t)(k0 + j) * NC + col]) : 0);
    *(bf16x8*)(Wtf + (size_t)f * 8) = v;
  } else if (bid < 912) {
    const int idx = bid - 112;   // 0..799
    const int r   = idx >> 3;    // 0..99
    const int ks  = idx & 7;     // K-slice of 256
    const int k0  = ks * 256;
    wcol[t] = W[(size_t)(k0 + t) * NC + r];
    arow[t] = A[(size_t)r * ND + k0 + t];
    __syncthreads();
    if (t < NC) {
      float g = 0.f, p = 0.f;
#pragma unroll 8
      for (int kk = 0; kk < 256; ++kk) {
        const float w = W[(size_t)(k0 + kk) * NC + t];
        g = fmaf(wcol[kk], w, g);
        p = fmaf(arow[kk], w, p);
      }
      atomicAdd(&G[r * NC + t], g);
      atomicAdd(&pa[r * NC + t], p);
    }
  } else {
    const int i = (bid - 912) * 256 + t;
    atomicAdd(&ihist[Y[i]], 1);
  }
}

// ---------------- prep2: T=softmax(pa)-I ; Ut[cp][r] = (G T^T)[r][cp] -------
__global__ __launch_bounds__(128) void k_prep2(const float* __restrict__ G,
                                               const float* __restrict__ pa,
                                               float* __restrict__ Ut) {
  __shared__ float vals[128];
  __shared__ float tl[128];
  const int cp = blockIdx.x;
  const int t  = threadIdx.x;
  const float v = (t < NC) ? pa[cp * NC + t] : -INFINITY;
  vals[t] = v;
  __syncthreads();
  float m = -INFINITY;
  for (int c = 0; c < NC; ++c) m = fmaxf(m, vals[c]);
  float se = 0.f;
  for (int c = 0; c < NC; ++c) se += __expf(vals[c] - m);
  tl[t] = (t < NC) ? (__expf(v - m) / se - (t == cp ? 1.f : 0.f)) : 0.f;
  __syncthreads();
  if (t < NC) {
    float u = 0.f;
    for (int c = 0; c < NC; ++c) u = fmaf(G[c * NC + t], tl[c], u);
    Ut[cp * NC + t] = u;
  }
}

// ---- main: stage X->LDS bf16 frag-major; 8 waves K-split; MFMA; epilogue ---
__global__ __launch_bounds__(512, 4) void k_main(const float* __restrict__ X,
                                                 const unsigned short* __restrict__ Wtf,
                                                 const int* __restrict__ Y,
                                                 const float* __restrict__ Ut,
                                                 float* __restrict__ S_total,
                                                 float* __restrict__ cls_ap,
                                                 float* __restrict__ sums) {
  __shared__ __align__(16) char smem[65536];  // Xf (64KB) then red(57KB)+stats
  const int t    = threadIdx.x;
  const int row0 = blockIdx.x * 16;

  // ---- stage: coalesced f32 loads -> bf16 -> fragment-major LDS ----
  {
    const int row = t >> 5;      // 0..15
    const int q   = t & 31;
    const float* __restrict__ xr = X + (size_t)(row0 + row) * ND;
    const int l = (q & 3) * 16 + row;   // lane owning this frag
#pragma unroll
    for (int j = 0; j < 8; ++j) {
      const int k0 = j * 256 + q * 8;
      const float4 v0 = *(const float4*)(xr + k0);
      const float4 v1 = *(const float4*)(xr + k0 + 4);
      bf16x8 p;
      p[0] = (short)f2bf(v0.x); p[1] = (short)f2bf(v0.y);
      p[2] = (short)f2bf(v0.z); p[3] = (short)f2bf(v0.w);
      p[4] = (short)f2bf(v1.x); p[5] = (short)f2bf(v1.y);
      p[6] = (short)f2bf(v1.z); p[7] = (short)f2bf(v1.w);
      const int ws = j * 8 + (q >> 2);
      *(bf16x8*)(smem + ws * 1024 + ((l * 16) ^ ((ws & 7) << 4))) = p;
    }
  }
  __syncthreads();

  const int w    = t >> 6;     // wave 0..7 = K-slice (256 K each)
  const int lane = t & 63;
  const int r    = lane & 15;
  const int g    = lane >> 4;

  f32x4 acc[7];
  const f32x4 z = {0.f, 0.f, 0.f, 0.f};
#pragma unroll
  for (int i = 0; i < 7; ++i) acc[i] = z;

#pragma unroll
  for (int s = 0; s < 8; ++s) {
    const int ws = w * 8 + s;
    const bf16x8 xf = *(const bf16x8*)(
        smem + ws * 1024 + ((lane * 16) ^ ((ws & 7) << 4)));
    const unsigned short* __restrict__ bp =
        Wtf + (size_t)(ws * 7) * 512 + lane * 8;
#pragma unroll
    for (int i = 0; i < 7; ++i) {
      const bf16x8 bf = *(const bf16x8*)(bp + i * 512);
      acc[i] = __builtin_amdgcn_mfma_f32_16x16x32_bf16(xf, bf, acc[i], 0, 0, 0);
    }
  }
  __syncthreads();  // all Xf reads done -> safe to reuse slab

  float* __restrict__ redp = (float*)smem;            // [8][7][4][64]
  float* __restrict__ sp   = (float*)(smem + 57344);  // [112] stacc, [112] ce, [113] ap
#pragma unroll
  for (int i = 0; i < 7; ++i)
#pragma unroll
    for (int j = 0; j < 4; ++j)
      redp[(w * 7 + i) * 256 + j * 64 + lane] = acc[i][j];
  if (t < 114) sp[t] = 0.f;
  __syncthreads();

  // epilogue: waves 0..3 each own j = w (rows g*4 + j)
  if (w < 4) {
    const int j = w;
    float v[7];
#pragma unroll
    for (int i = 0; i < 7; ++i) {
      float s = 0.f;
#pragma unroll
      for (int w2 = 0; w2 < 8; ++w2) s += redp[(w2 * 7 + i) * 256 + j * 64 + lane];
      v[i] = s;
    }
    const bool v6 = (96 + r) < NC;
    const int  yr = Y[row0 + g * 4 + j];

    float m = -INFINITY;
#pragma unroll
    for (int i = 0; i < 6; ++i) m = fmaxf(m, v[i]);
    if (v6) m = fmaxf(m, v[6]);
#pragma unroll
    for (int off = 8; off > 0; off >>= 1) m = fmaxf(m, __shfl_xor(m, off));

    float e[7];
    float se = 0.f, py = 0.f;
#pragma unroll
    for (int i = 0; i < 7; ++i) {
      const bool valid = (i < 6) | v6;
      e[i] = valid ? __expf(v[i] - m) : 0.f;
      se += e[i];
      if (i * 16 + r == yr) py = v[i];
    }
#pragma unroll
    for (int off = 8; off > 0; off >>= 1) {
      se += __shfl_xor(se, off);
      py += __shfl_xor(py, off);
    }
    const float ce  = m + __logf(se) - py;
    const float inv = 1.f / se;

    const float* __restrict__ uty = Ut + yr * NC;
    float ap = 0.f;
    float s[7];
#pragma unroll
    for (int i = 0; i < 7; ++i) {
      const int col = i * 16 + r;
      s[i] = e[i] * inv - (col == yr ? 1.f : 0.f);
      const float u = ((i < 6) | v6) ? uty[col] : 0.f;
      ap = fmaf(s[i], u, ap);
    }
#pragma unroll
    for (int off = 8; off > 0; off >>= 1) ap += __shfl_xor(ap, off);

    if (r == 0) {
      atomicAdd(&sp[112], ce);
      atomicAdd(&sp[113], ap);
      atomicAdd(&cls_ap[yr], ap);
    }
#pragma unroll
    for (int i = 0; i < 7; ++i) atomicAdd(&sp[i * 16 + r], s[i]);
  }
  __syncthreads();
  if (t < NC) atomicAdd(&S_total[t], sp[t]);
  if (t == 0) {
    atomicAdd(&sums[0], sp[112]);
    atomicAdd(&sums[1], sp[113]);
  }
}

// ---------------- final: V[c] dot + loss -----------------------------------
__global__ __launch_bounds__(128) void k_final(const int* __restrict__ ihist,
                                               const float* __restrict__ Ut,
                                               const float* __restrict__ S_total,
                                               const float* __restrict__ cls_ap,
                                               const float* __restrict__ sums,
                                               float* __restrict__ out) {
  __shared__ float st[NC];
  __shared__ float red[128];
  const int t = threadIdx.x;
  if (t < NC) st[t] = S_total[t];
  __syncthreads();
  float part = 0.f;
  if (t < NC) {
    float dot = 0.f;
    for (int r = 0; r < NC; ++r) dot = fmaf(st[r], Ut[t * NC + r], dot);
    part = (float)ihist[t] * (dot - cls_ap[t]);
  }
  red[t] = part;
  __syncthreads();
  for (int off = 64; off > 0; off >>= 1) {
    if (t < off) red[t] += red[t + off];
    __syncthreads();
  }
  if (t == 0) {
    out[0] = (sums[0] + ALPHA_ * (red[0] - sums[1] + (float)NB * MARGIN_)) /
             (float)NB;
  }
}

extern "C" void kernel_launch(void* const* d_in, const int* in_sizes, int n_in,
                              void* d_out, int out_size, void* d_ws,
                              size_t ws_size, hipStream_t stream) {
  const float* X = (const float*)d_in[0];
  const float* W = (const float*)d_in[1];
  const float* A = (const float*)d_in[2];
  const int*   Y = (const int*)d_in[3];
  float* out = (float*)d_out;
  char*  ws  = (char*)d_ws;

  float*          G       = (float*)(ws + 0);       // 40000 B
  float*          pa      = (float*)(ws + 40960);   // 40000 B
  float*          Ut      = (float*)(ws + 81920);   // 40000 B
  float*          S_total = (float*)(ws + 122880);  // 448 B
  float*          cls_ap  = (float*)(ws + 123392);  // 400 B
  float*          sums    = (float*)(ws + 123904);  // 8 B
  int*            ihist   = (int*)(ws + 124416);    // 400 B
  unsigned short* Wtf     = (unsigned short*)(ws + 131072);  // 458752 B

  hipMemsetAsync(ws, 0, 124928, stream);
  k_prep<<<944, 256, 0, stream>>>(W, A, Y, Wtf, G, pa, ihist);
  k_prep2<<<NC, 128, 0, stream>>>(G, pa, Ut);
  k_main<<<NB / 16, 512, 0, stream>>>(X, Wtf, Y, Ut, S_total, cls_ap, sums);
  k_final<<<1, 128, 0, stream>>>(ihist, Ut, S_total, cls_ap, sums, out);
}